// Round 4
// baseline (251.041 us; speedup 1.0000x reference)
//
#include <hip/hip_runtime.h>
#include <stdint.h>

#define SEQ    2048
#define DMODEL 1024
#define NH     16
#define HD     64
#define BATCH  4
#define MTOT   (BATCH*SEQ)   // 8192
#define NT     (SEQ/64)      // 32 K-tiles

typedef __attribute__((ext_vector_type(8))) short bf16x8;   // 8 bf16 = 4 VGPR
typedef __attribute__((ext_vector_type(4))) float f32x4;    // MFMA C/D frag
typedef __attribute__((ext_vector_type(2))) unsigned int uint2v;

#define QSCALE (0.125f * 1.44269504088896f)   // 1/sqrt(64) * log2(e)

// ---------- helpers ----------
__device__ __forceinline__ unsigned short f2bf(float f) {
  union { float f; uint32_t u; } x; x.f = f;
  uint32_t u = x.u;
  u += 0x7FFFu + ((u >> 16) & 1u);          // RNE
  return (unsigned short)(u >> 16);
}

__device__ __forceinline__ float exp2_fast(float x) {
#if __has_builtin(__builtin_amdgcn_exp2f)
  return __builtin_amdgcn_exp2f(x);
#else
  return __expf(x * 0.69314718056f);
#endif
}

__device__ __forceinline__ uint32_t cvt_pk_bf16(float lo, float hi) {
  uint32_t r;
  asm("v_cvt_pk_bf16_f32 %0, %1, %2" : "=v"(r) : "v"(lo), "v"(hi));
  return r;
}

// x' = {x[0:32], y[0:32]}, y' = {x[32:64], y[32:64]}
__device__ __forceinline__ void swap32(uint32_t& x, uint32_t& y) {
#if __has_builtin(__builtin_amdgcn_permlane32_swap)
  uint2v r = __builtin_amdgcn_permlane32_swap(x, y, false, false);
  x = r[0]; y = r[1];
#else
  unsigned int xs = __shfl_xor((unsigned int)x, 32);
  unsigned int ys = __shfl_xor((unsigned int)y, 32);
  const bool lo = ((threadIdx.x & 63) & 32) == 0;
  x = lo ? x : (uint32_t)ys;
  y = lo ? (uint32_t)xs : y;
#endif
}

// per 32-half: x' = {x[0:16], y[0:16]}, y' = {x[16:32], y[16:32]}
__device__ __forceinline__ void swap16(uint32_t& x, uint32_t& y) {
#if __has_builtin(__builtin_amdgcn_permlane16_swap)
  uint2v r = __builtin_amdgcn_permlane16_swap(x, y, false, false);
  x = r[0]; y = r[1];
#else
  unsigned int xs = __shfl_xor((unsigned int)x, 16);
  unsigned int ys = __shfl_xor((unsigned int)y, 16);
  const bool lo = ((threadIdx.x & 63) & 16) == 0;
  x = lo ? x : (uint32_t)ys;
  y = lo ? (uint32_t)xs : y;
#endif
}

__device__ __forceinline__ void gload_lds16(const ushort* g, ushort* l) {
  __builtin_amdgcn_global_load_lds(
      (const __attribute__((address_space(1))) uint32_t*)g,
      (__attribute__((address_space(3))) uint32_t*)l, 16, 0, 0);
}

// ---------- fp32 -> bf16 convert ----------
__global__ __launch_bounds__(256) void cvt_kernel(const float* __restrict__ in,
                                                  ushort* __restrict__ out, int n4) {
  int i = blockIdx.x * 256 + threadIdx.x;
  if (i >= n4) return;
  float4 v = ((const float4*)in)[i];
  ushort4 o;
  o.x = f2bf(v.x); o.y = f2bf(v.y); o.z = f2bf(v.z); o.w = f2bf(v.w);
  ((ushort4*)out)[i] = o;
}

// ---------- NT GEMM: C[M][N] = A[M][K] * B[N][K]^T + bias ----------
template<int MODE>
__global__ __launch_bounds__(256)
void gemm_nt(const ushort* __restrict__ A, const ushort* __restrict__ B,
             const float* __restrict__ bias, float* __restrict__ outf,
             ushort* __restrict__ qo, ushort* __restrict__ ko, ushort* __restrict__ vto,
             int M, int N, int K)
{
  __shared__ ushort lda[128 * 64];
  __shared__ ushort ldb[128 * 64];
  const int tid = threadIdx.x;
  const int w = tid >> 6, lane = tid & 63;
  const int l15 = lane & 15, lg = lane >> 4;
  const int row0 = blockIdx.y * 128;
  const int col0 = blockIdx.x * 128;
  const int wm = (w >> 1) * 64, wn = (w & 1) * 64;
  const int sr = lane >> 3, sc = (lane & 7) * 8;

  f32x4 acc[4][4];
#pragma unroll
  for (int i = 0; i < 4; ++i)
#pragma unroll
    for (int j = 0; j < 4; ++j) acc[i][j] = (f32x4){0.f, 0.f, 0.f, 0.f};

  const ushort* Ablk = A + (size_t)row0 * K;
  const ushort* Bblk = B + (size_t)col0 * K;

  for (int kt = 0; kt < K; kt += 64) {
#pragma unroll
    for (int i = 0; i < 4; ++i) {
      const int is = w * 4 + i;
      gload_lds16(Ablk + (size_t)(is * 8 + sr) * K + kt + sc, lda + is * 512);
      gload_lds16(Bblk + (size_t)(is * 8 + sr) * K + kt + sc, ldb + is * 512);
    }
    __syncthreads();
#pragma unroll
    for (int kk = 0; kk < 64; kk += 32) {
      bf16x8 af[4], bfr[4];
#pragma unroll
      for (int i = 0; i < 4; ++i)
        af[i] = *(const bf16x8*)&lda[(wm + i * 16 + l15) * 64 + kk + lg * 8];
#pragma unroll
      for (int j = 0; j < 4; ++j)
        bfr[j] = *(const bf16x8*)&ldb[(wn + j * 16 + l15) * 64 + kk + lg * 8];
#pragma unroll
      for (int i = 0; i < 4; ++i)
#pragma unroll
        for (int j = 0; j < 4; ++j)
          acc[i][j] = __builtin_amdgcn_mfma_f32_16x16x32_bf16(af[i], bfr[j], acc[i][j], 0, 0, 0);
    }
    __syncthreads();
  }

#pragma unroll
  for (int i = 0; i < 4; ++i)
#pragma unroll
    for (int j = 0; j < 4; ++j) {
      const int n = col0 + wn + j * 16 + l15;
      const int m0 = row0 + wm + i * 16 + lg * 4;
      const float bn = bias[n];
      if (MODE == 1) {
#pragma unroll
        for (int r = 0; r < 4; ++r)
          outf[(size_t)(m0 + r) * N + n] = acc[i][j][r] + bn;
      } else {
        const int d = n & 1023;
        const int hh = d >> 6, hd = d & 63;
        const int bb = m0 >> 11, ss0 = m0 & 2047;
        const int which = n >> 10;
        if (which == 2) {
          ushort4 pk;
          pk.x = f2bf(acc[i][j][0] + bn);
          pk.y = f2bf(acc[i][j][1] + bn);
          pk.z = f2bf(acc[i][j][2] + bn);
          pk.w = f2bf(acc[i][j][3] + bn);
          *(ushort4*)&vto[(((size_t)bb * NH + hh) * HD + hd) * SEQ + ss0] = pk;
        } else {
          const size_t idx = (((size_t)bb * NH + hh) * SEQ + ss0) * HD + hd;
#pragma unroll
          for (int r = 0; r < 4; ++r) {
            const float val = acc[i][j][r] + bn;
            if (which == 0) qo[idx + (size_t)r * HD] = f2bf(val * QSCALE);
            else            ko[idx + (size_t)r * HD] = f2bf(val);
          }
        }
      }
    }
}

// ---------- flash attention, swapped-QK^T, 8 waves, XCD-local K/V ----------
// 512 blocks x 512 threads. Block bid -> xcd = bid&7; all 8 q-tiles of one
// (b,h) run on the SAME XCD so K/V stay L2-resident (T1).
// S^T = mfma(K, Q): key = row, q = col -> row-reduce in-lane + 2 shuffles.
// P re-fragmented in-register via cvt_pk + permlane swaps. O^T = mfma(V^T,P^T).
__global__ __launch_bounds__(512)
void attn_kernel(const ushort* __restrict__ Q, const ushort* __restrict__ Kg,
                 const ushort* __restrict__ Vtg, ushort* __restrict__ O)
{
  __shared__ ushort ldk[2][64 * 64];     // swizzled K tiles (double buffer)
  __shared__ ushort ldvt[2][64 * 64];    // swizzled V^T tiles

  const int tid = threadIdx.x;
  const int w = tid >> 6, lane = tid & 63;
  const int l15 = lane & 15, lg = lane >> 4;

  // XCD-aware block remap: xcd c gets bh ≡ c (mod 8); consecutive j share bh.
  const int bid = blockIdx.x;
  const int c = bid & 7, j = bid >> 3;
  const int bh = c + 8 * (j >> 3);
  const int qt = j & 7;
  const int b = bh >> 4, h = bh & 15;

  const ushort* Qb = Q + (size_t)bh * SEQ * HD;
  const ushort* Kb = Kg + (size_t)bh * SEQ * HD;
  const ushort* Vtb = Vtg + (size_t)bh * HD * SEQ;

  const int srow = lane >> 3;            // staging row within 8-row chunk
  const int scb = (lane & 7) ^ srow;     // swizzled source col-block (16B units)
  const int rswz = l15 & 7;              // read-side XOR key

  // Q fragments (B-operand: col=q=l15, k=d=dk*32+lg*8)
  const int qr0 = qt * 256 + w * 32;
  bf16x8 qf[2][2];
#pragma unroll
  for (int mi = 0; mi < 2; ++mi)
#pragma unroll
    for (int dk = 0; dk < 2; ++dk)
      qf[mi][dk] = *(const bf16x8*)&Qb[(size_t)(qr0 + mi * 16 + l15) * HD + dk * 32 + lg * 8];

  f32x4 acc_o[2][4];                     // O^T: row hd = nf*16+lg*4+r, col q = l15
  float m_run[2], l_run[2];
#pragma unroll
  for (int mi = 0; mi < 2; ++mi) {
#pragma unroll
    for (int nf = 0; nf < 4; ++nf) acc_o[mi][nf] = (f32x4){0.f, 0.f, 0.f, 0.f};
    m_run[mi] = -1e30f; l_run[mi] = 0.f;
  }

  // 8 waves: each wave stages 1 KB of K and 1 KB of V^T per tile.
#define STAGE(bufi, tile) do {                                                          \
    gload_lds16(Kb + (size_t)(tile) * 64 * HD + (size_t)(w * 8 + srow) * HD + scb * 8,  \
                &ldk[bufi][w * 512]);                                                   \
    gload_lds16(Vtb + (size_t)(tile) * 64 + (size_t)(w * 8 + srow) * SEQ + scb * 8,     \
                &ldvt[bufi][w * 512]);                                                  \
  } while (0)

  int cur = 0;
  STAGE(0, 0);
  __syncthreads();

  for (int kt = 0; kt < NT; ++kt) {
    if (kt + 1 < NT) STAGE(cur ^ 1, kt + 1);   // prefetch overlaps compute below

    // --- S^T = K Q^T : accs[a][mi], key = a*16+lg*4+r, q = mi*16+l15 ---
    f32x4 accs[4][2];
#pragma unroll
    for (int a = 0; a < 4; ++a)
#pragma unroll
      for (int mi = 0; mi < 2; ++mi) accs[a][mi] = (f32x4){0.f, 0.f, 0.f, 0.f};
#pragma unroll
    for (int dk = 0; dk < 2; ++dk) {
      bf16x8 kfr[4];
#pragma unroll
      for (int a = 0; a < 4; ++a)
        kfr[a] = *(const bf16x8*)&ldk[cur][(a * 16 + l15) * 64 + ((dk * 4 + lg) ^ rswz) * 8];
      __builtin_amdgcn_s_setprio(1);
#pragma unroll
      for (int a = 0; a < 4; ++a)
#pragma unroll
        for (int mi = 0; mi < 2; ++mi)
          accs[a][mi] = __builtin_amdgcn_mfma_f32_16x16x32_bf16(kfr[a], qf[mi][dk], accs[a][mi], 0, 0, 0);
      __builtin_amdgcn_s_setprio(0);
    }

    // --- online softmax (log2 domain), in-lane tree + 2 shuffles per mi ---
#pragma unroll
    for (int mi = 0; mi < 2; ++mi) {
      float t0 = fmaxf(fmaxf(accs[0][mi][0], accs[0][mi][1]), fmaxf(accs[0][mi][2], accs[0][mi][3]));
      float t1 = fmaxf(fmaxf(accs[1][mi][0], accs[1][mi][1]), fmaxf(accs[1][mi][2], accs[1][mi][3]));
      float t2 = fmaxf(fmaxf(accs[2][mi][0], accs[2][mi][1]), fmaxf(accs[2][mi][2], accs[2][mi][3]));
      float t3 = fmaxf(fmaxf(accs[3][mi][0], accs[3][mi][1]), fmaxf(accs[3][mi][2], accs[3][mi][3]));
      float mx = fmaxf(fmaxf(t0, t1), fmaxf(t2, t3));
      mx = fmaxf(mx, __shfl_xor(mx, 16));
      mx = fmaxf(mx, __shfl_xor(mx, 32));
      if (!__all(mx - m_run[mi] <= 8.0f)) {          // T13 defer-max
        const float mnew = fmaxf(m_run[mi], mx);
        const float corr = exp2_fast(m_run[mi] - mnew);
        l_run[mi] *= corr;
#pragma unroll
        for (int nf = 0; nf < 4; ++nf)
#pragma unroll
          for (int r = 0; r < 4; ++r) acc_o[mi][nf][r] *= corr;
        m_run[mi] = mnew;
      }
      const float m = m_run[mi];
      float ps = 0.f;
#pragma unroll
      for (int a = 0; a < 4; ++a)
#pragma unroll
        for (int r = 0; r < 4; ++r) {
          const float p = exp2_fast(accs[a][mi][r] - m);
          accs[a][mi][r] = p;
          ps += p;
        }
      ps += __shfl_xor(ps, 16);
      ps += __shfl_xor(ps, 32);
      l_run[mi] += ps;
    }

    // --- O^T += V^T P^T; P^T re-fragmented in-register ---
#pragma unroll
    for (int kk = 0; kk < 2; ++kk) {
      bf16x8 vv[4];
#pragma unroll
      for (int nf = 0; nf < 4; ++nf)
        vv[nf] = *(const bf16x8*)&ldvt[cur][(nf * 16 + l15) * 64 + ((kk * 4 + lg) ^ rswz) * 8];
#pragma unroll
      for (int mi = 0; mi < 2; ++mi) {
        uint32_t a0 = cvt_pk_bf16(accs[2 * kk][mi][0], accs[2 * kk][mi][1]);
        uint32_t a1 = cvt_pk_bf16(accs[2 * kk][mi][2], accs[2 * kk][mi][3]);
        uint32_t b0 = cvt_pk_bf16(accs[2 * kk + 1][mi][0], accs[2 * kk + 1][mi][1]);
        uint32_t b1 = cvt_pk_bf16(accs[2 * kk + 1][mi][2], accs[2 * kk + 1][mi][3]);
        swap32(a0, b0); swap32(a1, b1);
        swap16(a0, b0); swap16(a1, b1);
        union { uint32_t d[4]; bf16x8 v; } pu;
        pu.d[0] = a0; pu.d[1] = a1; pu.d[2] = b0; pu.d[3] = b1;
        __builtin_amdgcn_s_setprio(1);
#pragma unroll
        for (int nf = 0; nf < 4; ++nf)
          acc_o[mi][nf] = __builtin_amdgcn_mfma_f32_16x16x32_bf16(vv[nf], pu.v, acc_o[mi][nf], 0, 0, 0);
        __builtin_amdgcn_s_setprio(0);
      }
    }

    __syncthreads();   // drains prefetch (overlapped) + protects buffer reuse
    cur ^= 1;
  }
#undef STAGE

  // --- epilogue: O^T -> O, packed ushort4 (hd contiguous per lane) ---
#pragma unroll
  for (int mi = 0; mi < 2; ++mi) {
    const float rl = 1.0f / l_run[mi];
    const int row = b * SEQ + qr0 + mi * 16 + l15;
#pragma unroll
    for (int nf = 0; nf < 4; ++nf) {
      ushort4 pk;
      pk.x = f2bf(acc_o[mi][nf][0] * rl);
      pk.y = f2bf(acc_o[mi][nf][1] * rl);
      pk.z = f2bf(acc_o[mi][nf][2] * rl);
      pk.w = f2bf(acc_o[mi][nf][3] * rl);
      *(ushort4*)&O[(size_t)row * DMODEL + h * HD + nf * 16 + lg * 4] = pk;
    }
  }
}

// ---------- launch ----------
extern "C" void kernel_launch(void* const* d_in, const int* in_sizes, int n_in,
                              void* d_out, int out_size, void* d_ws, size_t ws_size,
                              hipStream_t stream) {
  const float* x     = (const float*)d_in[0];
  const float* Wqkv  = (const float*)d_in[1];
  const float* bqkv  = (const float*)d_in[2];
  const float* Wproj = (const float*)d_in[3];
  const float* bproj = (const float*)d_in[4];
  float* out = (float*)d_out;

  char* ws = (char*)d_ws;
  ushort* x_bf     = (ushort*)ws;                      // 16MB (reused as attn-out)
  ushort* ao       = x_bf;
  ushort* wqkv_bf  = (ushort*)(ws + (16u << 20));      // 6MB
  ushort* wproj_bf = (ushort*)(ws + (22u << 20));      // 2MB
  ushort* q        = (ushort*)(ws + (24u << 20));      // 16MB each
  ushort* k        = (ushort*)(ws + (40u << 20));
  ushort* vt       = (ushort*)(ws + (56u << 20));      // V transposed [B,H,HD,SEQ]

  cvt_kernel<<<(MTOT * DMODEL / 4) / 256, 256, 0, stream>>>(x, x_bf, MTOT * DMODEL / 4);
  cvt_kernel<<<(3 * DMODEL * DMODEL / 4) / 256, 256, 0, stream>>>(Wqkv, wqkv_bf, 3 * DMODEL * DMODEL / 4);
  cvt_kernel<<<(DMODEL * DMODEL / 4) / 256, 256, 0, stream>>>(Wproj, wproj_bf, DMODEL * DMODEL / 4);

  gemm_nt<0><<<dim3(3 * DMODEL / 128, MTOT / 128), 256, 0, stream>>>(
      x_bf, wqkv_bf, bqkv, nullptr, q, k, vt, MTOT, 3 * DMODEL, DMODEL);

  attn_kernel<<<dim3(512), 512, 0, stream>>>(q, k, vt, ao);

  gemm_nt<1><<<dim3(DMODEL / 128, MTOT / 128), 256, 0, stream>>>(
      ao, wproj_bf, bproj, out, nullptr, nullptr, nullptr, MTOT, DMODEL, DMODEL);
}